// Round 1
// baseline (2590.550 us; speedup 1.0000x reference)
//
#include <hip/hip_runtime.h>

#define NU 100000
#define NM 50000
#define HDIM 64

__device__ __forceinline__ float bcastf(float v, int lane) {
  return __int_as_float(__builtin_amdgcn_readlane(__float_as_int(v), lane));
}

__global__ void k_count(const int* __restrict__ src, const int* __restrict__ dst,
                        int* cnt_u, int* cnt_m, int E) {
  int e = blockIdx.x * blockDim.x + threadIdx.x;
  if (e < E) {
    atomicAdd(&cnt_u[src[e]], 1);
    atomicAdd(&cnt_m[dst[e]], 1);
  }
}

// per-block (1024 elems) exclusive scan; writes local-exclusive offsets + block sum
__global__ void k_scan_part(const int* __restrict__ cnt, int* __restrict__ off,
                            int* __restrict__ bsum, int n) {
  __shared__ int wsum[4];
  int t = threadIdx.x;
  int base = blockIdx.x * 1024 + t * 4;
  int v0 = (base + 0 < n) ? cnt[base + 0] : 0;
  int v1 = (base + 1 < n) ? cnt[base + 1] : 0;
  int v2 = (base + 2 < n) ? cnt[base + 2] : 0;
  int v3 = (base + 3 < n) ? cnt[base + 3] : 0;
  int s = v0 + v1 + v2 + v3;
  int lane = t & 63;
  int inc = s;
  #pragma unroll
  for (int d = 1; d < 64; d <<= 1) {
    int x = __shfl_up(inc, d);
    if (lane >= d) inc += x;
  }
  int wid = t >> 6;
  if (lane == 63) wsum[wid] = inc;
  __syncthreads();
  int woff = 0;
  for (int i = 0; i < wid; i++) woff += wsum[i];
  int excl = woff + inc - s;
  if (base + 0 < n) off[base + 0] = excl;
  if (base + 1 < n) off[base + 1] = excl + v0;
  if (base + 2 < n) off[base + 2] = excl + v0 + v1;
  if (base + 3 < n) off[base + 3] = excl + v0 + v1 + v2;
  if (t == 255) bsum[blockIdx.x] = woff + inc;
}

// in-place exclusive scan of block sums (nb <= ~100), single wave
__global__ void k_scan_top(int* bsum, int nb) {
  int lane = threadIdx.x;  // block of 64
  int carry = 0;
  for (int base = 0; base < nb; base += 64) {
    int i = base + lane;
    int v = (i < nb) ? bsum[i] : 0;
    int inc = v;
    #pragma unroll
    for (int d = 1; d < 64; d <<= 1) {
      int x = __shfl_up(inc, d);
      if (lane >= d) inc += x;
    }
    if (i < nb) bsum[i] = carry + inc - v;
    carry += __shfl(inc, 63);
  }
}

__global__ void k_scan_add(int* __restrict__ off, int* __restrict__ cur,
                           const int* __restrict__ bsum, int n, int total) {
  int i = blockIdx.x * blockDim.x + threadIdx.x;
  if (i < n) {
    int v = off[i] + bsum[i >> 10];
    off[i] = v;
    cur[i] = v;
  } else if (i == n) {
    off[n] = total;
  }
}

__global__ void k_scatter(const int* __restrict__ src, const int* __restrict__ dst,
                          int* cur_u, int* cur_m,
                          int* __restrict__ nbr_u, int* __restrict__ nbr_m, int E) {
  int e = blockIdx.x * blockDim.x + threadIdx.x;
  if (e < E) {
    int s = src[e], d = dst[e];
    int pu = atomicAdd(&cur_u[s], 1);
    nbr_u[pu] = d;
    int pm = atomicAdd(&cur_m[d], 1);
    nbr_m[pm] = s;
  }
}

// x_movie = movie_x @ lin_W.T + lin_b + movie_emb  (wave per movie, lane = h)
__global__ void k_movie_init(const float* __restrict__ movie_x,
                             const float* __restrict__ lin_W,
                             const float* __restrict__ lin_b,
                             const float* __restrict__ movie_emb,
                             float* __restrict__ x_movie) {
  int w = (blockIdx.x * blockDim.x + threadIdx.x) >> 6;
  int h = threadIdx.x & 63;
  if (w >= NM) return;
  float acc = lin_b[h] + movie_emb[(size_t)w * 64 + h];
  const float* mx = movie_x + (size_t)w * 20;
  const float* lw = lin_W + (size_t)h * 20;
  #pragma unroll
  for (int f = 0; f < 20; f++) acc += mx[f] * lw[f];
  x_movie[(size_t)w * 64 + h] = acc;
}

// One wave per destination node. lane = feature h.
// out[i][h] = sum_k mean[i][k]*Wl[h][k] + sum_k xdst[i][k]*Wr[h][k] + b[h]
// Wl/Wr rows held in VGPRs; cross-lane broadcast via v_readlane.
template <int RELU>
__global__ void __launch_bounds__(256)
k_agg(const float* __restrict__ xsrc, const float* __restrict__ xdst,
      const int* __restrict__ nbr, const int* __restrict__ off,
      const float* __restrict__ Wl, const float* __restrict__ Wr,
      const float* __restrict__ bias, float* __restrict__ out, int ndst) {
  int w = (blockIdx.x * blockDim.x + threadIdx.x) >> 6;
  int h = threadIdx.x & 63;
  if (w >= ndst) return;  // wave-uniform
  float wl[64], wr[64];
  const float4* wl4 = (const float4*)(Wl + (size_t)h * 64);
  const float4* wr4 = (const float4*)(Wr + (size_t)h * 64);
  #pragma unroll
  for (int i = 0; i < 16; i++) {
    float4 a = wl4[i];
    wl[4 * i] = a.x; wl[4 * i + 1] = a.y; wl[4 * i + 2] = a.z; wl[4 * i + 3] = a.w;
    float4 c = wr4[i];
    wr[4 * i] = c.x; wr[4 * i + 1] = c.y; wr[4 * i + 2] = c.z; wr[4 * i + 3] = c.w;
  }
  float bv = bias[h];
  int s = off[w], e = off[w + 1];
  float s0 = 0.f, s1 = 0.f, s2 = 0.f, s3 = 0.f;
  int k = s;
  for (; k + 4 <= e; k += 4) {
    int j0 = nbr[k], j1 = nbr[k + 1], j2 = nbr[k + 2], j3 = nbr[k + 3];
    s0 += xsrc[(size_t)j0 * 64 + h];
    s1 += xsrc[(size_t)j1 * 64 + h];
    s2 += xsrc[(size_t)j2 * 64 + h];
    s3 += xsrc[(size_t)j3 * 64 + h];
  }
  for (; k < e; k++) s0 += xsrc[(size_t)nbr[k] * 64 + h];
  float sum = (s0 + s1) + (s2 + s3);
  float inv = 1.0f / fmaxf((float)(e - s), 1.0f);
  float mean = sum * inv;
  float dv = xdst[(size_t)w * 64 + h];
  float acc = bv;
  #pragma unroll
  for (int kk = 0; kk < 64; kk++) {
    acc += bcastf(mean, kk) * wl[kk];
    acc += bcastf(dv, kk) * wr[kk];
  }
  if (RELU) acc = fmaxf(acc, 0.0f);
  out[(size_t)w * 64 + h] = acc;
}

__global__ void k_dot(const float* __restrict__ u2, const float* __restrict__ m2,
                      const int* __restrict__ eu, const int* __restrict__ em,
                      float* __restrict__ out, int L) {
  int l = blockIdx.x * blockDim.x + threadIdx.x;
  if (l >= L) return;
  const float4* a = (const float4*)(u2 + (size_t)eu[l] * 64);
  const float4* b = (const float4*)(m2 + (size_t)em[l] * 64);
  float s = 0.f;
  #pragma unroll
  for (int i = 0; i < 16; i++) {
    float4 x = a[i], y = b[i];
    s += x.x * y.x + x.y * y.y + x.z * y.z + x.w * y.w;
  }
  out[l] = s;
}

extern "C" void kernel_launch(void* const* d_in, const int* in_sizes, int n_in,
                              void* d_out, int out_size, void* d_ws, size_t ws_size,
                              hipStream_t stream) {
  const float* movie_x   = (const float*)d_in[2];
  const int*   esrc      = (const int*)d_in[3];
  const int*   edst      = (const int*)d_in[4];
  const int*   eli_u     = (const int*)d_in[5];
  const int*   eli_m     = (const int*)d_in[6];
  const float* user_emb  = (const float*)d_in[7];
  const float* movie_emb = (const float*)d_in[8];
  const float* lin_W     = (const float*)d_in[9];
  const float* lin_b     = (const float*)d_in[10];
  const float* W1um_l = (const float*)d_in[11];
  const float* W1um_r = (const float*)d_in[12];
  const float* W1mu_l = (const float*)d_in[13];
  const float* W1mu_r = (const float*)d_in[14];
  const float* W2um_l = (const float*)d_in[15];
  const float* W2um_r = (const float*)d_in[16];
  const float* W2mu_l = (const float*)d_in[17];
  const float* W2mu_r = (const float*)d_in[18];
  const float* b1um = (const float*)d_in[19];
  const float* b1mu = (const float*)d_in[20];
  const float* b2um = (const float*)d_in[21];
  const float* b2mu = (const float*)d_in[22];
  const int E = in_sizes[3];
  const int L = in_sizes[5];

  char* ws = (char*)d_ws;
  size_t o = 0;
  auto alloc = [&](size_t bytes) -> void* {
    void* p = ws + o;
    o = (o + bytes + 255) & ~(size_t)255;
    return p;
  };
  float* x_movie = (float*)alloc((size_t)NM * 64 * 4);
  float* m1      = (float*)alloc((size_t)NM * 64 * 4);
  float* u1      = (float*)alloc((size_t)NU * 64 * 4);
  float* m2      = (float*)alloc((size_t)NM * 64 * 4);
  float* u2      = (float*)alloc((size_t)NU * 64 * 4);
  int* cnt_m = (int*)alloc((size_t)NM * 4);
  int* cnt_u = (int*)alloc((size_t)NU * 4);
  int* off_m = (int*)alloc((size_t)(NM + 1) * 4);
  int* off_u = (int*)alloc((size_t)(NU + 1) * 4);
  int* cur_m = (int*)alloc((size_t)NM * 4);
  int* cur_u = (int*)alloc((size_t)NU * 4);
  int* bs_m  = (int*)alloc(4096);
  int* bs_u  = (int*)alloc(4096);
  int* nbr_m = (int*)alloc((size_t)E * 4);
  int* nbr_u = (int*)alloc((size_t)E * 4);

  hipMemsetAsync(cnt_m, 0, (size_t)NM * 4, stream);
  hipMemsetAsync(cnt_u, 0, (size_t)NU * 4, stream);

  int gE = (E + 255) / 256;
  k_count<<<gE, 256, 0, stream>>>(esrc, edst, cnt_u, cnt_m, E);

  int nbm = (NM + 1023) / 1024, nbu = (NU + 1023) / 1024;
  k_scan_part<<<nbm, 256, 0, stream>>>(cnt_m, off_m, bs_m, NM);
  k_scan_part<<<nbu, 256, 0, stream>>>(cnt_u, off_u, bs_u, NU);
  k_scan_top<<<1, 64, 0, stream>>>(bs_m, nbm);
  k_scan_top<<<1, 64, 0, stream>>>(bs_u, nbu);
  k_scan_add<<<(NM + 1 + 255) / 256, 256, 0, stream>>>(off_m, cur_m, bs_m, NM, E);
  k_scan_add<<<(NU + 1 + 255) / 256, 256, 0, stream>>>(off_u, cur_u, bs_u, NU, E);
  k_scatter<<<gE, 256, 0, stream>>>(esrc, edst, cur_u, cur_m, nbr_u, nbr_m, E);

  k_movie_init<<<(NM + 3) / 4, 256, 0, stream>>>(movie_x, lin_W, lin_b, movie_emb, x_movie);

  // layer 1 (ReLU)
  k_agg<1><<<(NM + 3) / 4, 256, 0, stream>>>(user_emb, x_movie, nbr_m, off_m,
                                             W1um_l, W1um_r, b1um, m1, NM);
  k_agg<1><<<(NU + 3) / 4, 256, 0, stream>>>(x_movie, user_emb, nbr_u, off_u,
                                             W1mu_l, W1mu_r, b1mu, u1, NU);
  // layer 2 (no activation)
  k_agg<0><<<(NM + 3) / 4, 256, 0, stream>>>(u1, m1, nbr_m, off_m,
                                             W2um_l, W2um_r, b2um, m2, NM);
  k_agg<0><<<(NU + 3) / 4, 256, 0, stream>>>(m1, u1, nbr_u, off_u,
                                             W2mu_l, W2mu_r, b2mu, u2, NU);

  k_dot<<<(L + 255) / 256, 256, 0, stream>>>(u2, m2, eli_u, eli_m, (float*)d_out, L);
}

// Round 3
// 2139.329 us; speedup vs baseline: 1.2109x; 1.2109x over previous
//
#include <hip/hip_runtime.h>

#define NU 100000
#define NM 50000
#define HDIM 64

__device__ __forceinline__ float bcastf(float v, int lane) {
  return __int_as_float(__builtin_amdgcn_readlane(__float_as_int(v), lane));
}

__global__ void k_count(const int* __restrict__ src, const int* __restrict__ dst,
                        int* cnt_u, int* cnt_m, int E) {
  int e = blockIdx.x * blockDim.x + threadIdx.x;
  if (e < E) {
    atomicAdd(&cnt_u[src[e]], 1);
    atomicAdd(&cnt_m[dst[e]], 1);
  }
}

// per-block (1024 elems) exclusive scan; writes local-exclusive offsets + block sum
__global__ void k_scan_part(const int* __restrict__ cnt, int* __restrict__ off,
                            int* __restrict__ bsum, int n) {
  __shared__ int wsum[4];
  int t = threadIdx.x;
  int base = blockIdx.x * 1024 + t * 4;
  int v0 = (base + 0 < n) ? cnt[base + 0] : 0;
  int v1 = (base + 1 < n) ? cnt[base + 1] : 0;
  int v2 = (base + 2 < n) ? cnt[base + 2] : 0;
  int v3 = (base + 3 < n) ? cnt[base + 3] : 0;
  int s = v0 + v1 + v2 + v3;
  int lane = t & 63;
  int inc = s;
  #pragma unroll
  for (int d = 1; d < 64; d <<= 1) {
    int x = __shfl_up(inc, d);
    if (lane >= d) inc += x;
  }
  int wid = t >> 6;
  if (lane == 63) wsum[wid] = inc;
  __syncthreads();
  int woff = 0;
  for (int i = 0; i < wid; i++) woff += wsum[i];
  int excl = woff + inc - s;
  if (base + 0 < n) off[base + 0] = excl;
  if (base + 1 < n) off[base + 1] = excl + v0;
  if (base + 2 < n) off[base + 2] = excl + v0 + v1;
  if (base + 3 < n) off[base + 3] = excl + v0 + v1 + v2;
  if (t == 255) bsum[blockIdx.x] = woff + inc;
}

// in-place exclusive scan of block sums, single wave
__global__ void k_scan_top(int* bsum, int nb) {
  int lane = threadIdx.x;  // block of 64
  int carry = 0;
  for (int base = 0; base < nb; base += 64) {
    int i = base + lane;
    int v = (i < nb) ? bsum[i] : 0;
    int inc = v;
    #pragma unroll
    for (int d = 1; d < 64; d <<= 1) {
      int x = __shfl_up(inc, d);
      if (lane >= d) inc += x;
    }
    if (i < nb) bsum[i] = carry + inc - v;
    carry += __shfl(inc, 63);
  }
}

__global__ void k_scan_add(int* __restrict__ off, int* __restrict__ cur,
                           const int* __restrict__ bsum, int n, int total) {
  int i = blockIdx.x * blockDim.x + threadIdx.x;
  if (i < n) {
    int v = off[i] + bsum[i >> 10];
    off[i] = v;
    cur[i] = v;
  } else if (i == n) {
    off[n] = total;
  }
}

__global__ void k_scatter(const int* __restrict__ src, const int* __restrict__ dst,
                          int* cur_u, int* cur_m,
                          int* __restrict__ nbr_u, int* __restrict__ nbr_m, int E) {
  int e = blockIdx.x * blockDim.x + threadIdx.x;
  if (e < E) {
    int s = src[e], d = dst[e];
    int pu = atomicAdd(&cur_u[s], 1);
    nbr_u[pu] = d;
    int pm = atomicAdd(&cur_m[d], 1);
    nbr_m[pm] = s;
  }
}

// x_movie = movie_x @ lin_W.T + lin_b + movie_emb  (wave per movie, lane = h)
__global__ void k_movie_init(const float* __restrict__ movie_x,
                             const float* __restrict__ lin_W,
                             const float* __restrict__ lin_b,
                             const float* __restrict__ movie_emb,
                             float* __restrict__ x_movie) {
  int w = (blockIdx.x * blockDim.x + threadIdx.x) >> 6;
  int h = threadIdx.x & 63;
  if (w >= NM) return;
  float acc = lin_b[h] + movie_emb[(size_t)w * 64 + h];
  const float* mx = movie_x + (size_t)w * 20;
  const float* lw = lin_W + (size_t)h * 20;
  #pragma unroll
  for (int f = 0; f < 20; f++) acc += mx[f] * lw[f];
  x_movie[(size_t)w * 64 + h] = acc;
}

// One wave per destination node (movie dests first, then user dests in the
// same grid so both relations' latency-bound waves are co-resident).
// lane = feature h. Neighbor indices preloaded coalesced (nbr[base+lane]),
// broadcast via v_readlane into SGPRs -> gathers are scalar-base + h*4.
// 8 independent accumulator chains for memory-level parallelism; tail is
// handled with clamped index + cndmask so MLP stays 8-deep.
template <int RELU>
__global__ void __launch_bounds__(256)
k_agg_dual(const float* __restrict__ xu, const float* __restrict__ xm,
           const int* __restrict__ nbrM, const int* __restrict__ offM,
           const float* __restrict__ WlM, const float* __restrict__ WrM,
           const float* __restrict__ bM, float* __restrict__ outM,
           const int* __restrict__ nbrU, const int* __restrict__ offU,
           const float* __restrict__ WlU, const float* __restrict__ WrU,
           const float* __restrict__ bU, float* __restrict__ outU) {
  int gw = (blockIdx.x * blockDim.x + threadIdx.x) >> 6;
  int h = threadIdx.x & 63;
  if (gw >= NM + NU) return;  // wave-uniform
  const float* xsrc;
  const float* xdst;
  const int* nbr;
  const int* off;
  const float* Wl;
  const float* Wr;
  const float* bias;
  float* out;
  int w;
  if (gw < NM) {
    w = gw; xsrc = xu; xdst = xm; nbr = nbrM; off = offM;
    Wl = WlM; Wr = WrM; bias = bM; out = outM;
  } else {
    w = gw - NM; xsrc = xm; xdst = xu; nbr = nbrU; off = offU;
    Wl = WlU; Wr = WrU; bias = bU; out = outU;
  }
  int s = off[w], e = off[w + 1];
  float a0 = 0.f, a1 = 0.f, a2 = 0.f, a3 = 0.f;
  float a4 = 0.f, a5 = 0.f, a6 = 0.f, a7 = 0.f;
  for (int base = s; base < e; base += 64) {
    int cn = e - base;
    if (cn > 64) cn = 64;
    int my = nbr[base + (h < cn ? h : 0)];  // one coalesced load per 64 nbrs
    for (int g = 0; g < cn; g += 8) {
      int lim = cn - 1;
      int j0 = __builtin_amdgcn_readlane(my, min(g + 0, lim));
      int j1 = __builtin_amdgcn_readlane(my, min(g + 1, lim));
      int j2 = __builtin_amdgcn_readlane(my, min(g + 2, lim));
      int j3 = __builtin_amdgcn_readlane(my, min(g + 3, lim));
      int j4 = __builtin_amdgcn_readlane(my, min(g + 4, lim));
      int j5 = __builtin_amdgcn_readlane(my, min(g + 5, lim));
      int j6 = __builtin_amdgcn_readlane(my, min(g + 6, lim));
      int j7 = __builtin_amdgcn_readlane(my, min(g + 7, lim));
      float v0 = xsrc[(size_t)j0 * 64 + h];
      float v1 = xsrc[(size_t)j1 * 64 + h];
      float v2 = xsrc[(size_t)j2 * 64 + h];
      float v3 = xsrc[(size_t)j3 * 64 + h];
      float v4 = xsrc[(size_t)j4 * 64 + h];
      float v5 = xsrc[(size_t)j5 * 64 + h];
      float v6 = xsrc[(size_t)j6 * 64 + h];
      float v7 = xsrc[(size_t)j7 * 64 + h];
      a0 += (g + 0 < cn) ? v0 : 0.f;
      a1 += (g + 1 < cn) ? v1 : 0.f;
      a2 += (g + 2 < cn) ? v2 : 0.f;
      a3 += (g + 3 < cn) ? v3 : 0.f;
      a4 += (g + 4 < cn) ? v4 : 0.f;
      a5 += (g + 5 < cn) ? v5 : 0.f;
      a6 += (g + 6 < cn) ? v6 : 0.f;
      a7 += (g + 7 < cn) ? v7 : 0.f;
    }
  }
  float sum = ((a0 + a1) + (a2 + a3)) + ((a4 + a5) + (a6 + a7));
  float inv = 1.0f / fmaxf((float)(e - s), 1.0f);
  float mean = sum * inv;
  float dv = xdst[(size_t)w * 64 + h];
  // transform epilogue: weight rows in VGPRs, broadcast activations via readlane
  float wl[64], wr[64];
  const float4* wl4 = (const float4*)(Wl + (size_t)h * 64);
  const float4* wr4 = (const float4*)(Wr + (size_t)h * 64);
  #pragma unroll
  for (int i = 0; i < 16; i++) {
    float4 a = wl4[i];
    wl[4 * i] = a.x; wl[4 * i + 1] = a.y; wl[4 * i + 2] = a.z; wl[4 * i + 3] = a.w;
    float4 c = wr4[i];
    wr[4 * i] = c.x; wr[4 * i + 1] = c.y; wr[4 * i + 2] = c.z; wr[4 * i + 3] = c.w;
  }
  float acc = bias[h];
  #pragma unroll
  for (int kk = 0; kk < 64; kk++) {
    acc += bcastf(mean, kk) * wl[kk];
    acc += bcastf(dv, kk) * wr[kk];
  }
  if (RELU) acc = fmaxf(acc, 0.0f);
  out[(size_t)w * 64 + h] = acc;
}

// 16 lanes per edge: float4 row reads are 256B contiguous per row,
// shfl_xor reduce within the 16-lane group, 4 consecutive stores per wave.
// Each 256-thread block covers 4 waves * 4 edges = 16 edges.
__global__ void __launch_bounds__(256)
k_dot(const float* __restrict__ u2, const float* __restrict__ m2,
      const int* __restrict__ eu, const int* __restrict__ em,
      float* __restrict__ out, int L) {
  int wave = (blockIdx.x * blockDim.x + threadIdx.x) >> 6;
  int lane = threadIdx.x & 63;
  int sub = lane & 15;
  int l = wave * 4 + (lane >> 4);
  int lc = l < L ? l : (L - 1);
  int iu = eu[lc], im = em[lc];
  float4 x = ((const float4*)(u2 + (size_t)iu * 64))[sub];
  float4 y = ((const float4*)(m2 + (size_t)im * 64))[sub];
  float s = x.x * y.x + x.y * y.y + x.z * y.z + x.w * y.w;
  s += __shfl_xor(s, 1);
  s += __shfl_xor(s, 2);
  s += __shfl_xor(s, 4);
  s += __shfl_xor(s, 8);
  if (sub == 0 && l < L) out[l] = s;
}

extern "C" void kernel_launch(void* const* d_in, const int* in_sizes, int n_in,
                              void* d_out, int out_size, void* d_ws, size_t ws_size,
                              hipStream_t stream) {
  const float* movie_x   = (const float*)d_in[2];
  const int*   esrc      = (const int*)d_in[3];
  const int*   edst      = (const int*)d_in[4];
  const int*   eli_u     = (const int*)d_in[5];
  const int*   eli_m     = (const int*)d_in[6];
  const float* user_emb  = (const float*)d_in[7];
  const float* movie_emb = (const float*)d_in[8];
  const float* lin_W     = (const float*)d_in[9];
  const float* lin_b     = (const float*)d_in[10];
  const float* W1um_l = (const float*)d_in[11];
  const float* W1um_r = (const float*)d_in[12];
  const float* W1mu_l = (const float*)d_in[13];
  const float* W1mu_r = (const float*)d_in[14];
  const float* W2um_l = (const float*)d_in[15];
  const float* W2um_r = (const float*)d_in[16];
  const float* W2mu_l = (const float*)d_in[17];
  const float* W2mu_r = (const float*)d_in[18];
  const float* b1um = (const float*)d_in[19];
  const float* b1mu = (const float*)d_in[20];
  const float* b2um = (const float*)d_in[21];
  const float* b2mu = (const float*)d_in[22];
  const int E = in_sizes[3];
  const int L = in_sizes[5];

  char* ws = (char*)d_ws;
  size_t o = 0;
  auto alloc = [&](size_t bytes) -> void* {
    void* p = ws + o;
    o = (o + bytes + 255) & ~(size_t)255;
    return p;
  };
  float* x_movie = (float*)alloc((size_t)NM * 64 * 4);
  float* m1      = (float*)alloc((size_t)NM * 64 * 4);
  float* u1      = (float*)alloc((size_t)NU * 64 * 4);
  float* m2      = (float*)alloc((size_t)NM * 64 * 4);
  float* u2      = (float*)alloc((size_t)NU * 64 * 4);
  int* cnt_m = (int*)alloc((size_t)NM * 4);
  int* cnt_u = (int*)alloc((size_t)NU * 4);
  int* off_m = (int*)alloc((size_t)(NM + 1) * 4);
  int* off_u = (int*)alloc((size_t)(NU + 1) * 4);
  int* cur_m = (int*)alloc((size_t)NM * 4);
  int* cur_u = (int*)alloc((size_t)NU * 4);
  int* bs_m  = (int*)alloc(4096);
  int* bs_u  = (int*)alloc(4096);
  int* nbr_m = (int*)alloc((size_t)E * 4);
  int* nbr_u = (int*)alloc((size_t)E * 4);

  hipMemsetAsync(cnt_m, 0, (size_t)NM * 4, stream);
  hipMemsetAsync(cnt_u, 0, (size_t)NU * 4, stream);

  int gE = (E + 255) / 256;
  k_count<<<gE, 256, 0, stream>>>(esrc, edst, cnt_u, cnt_m, E);

  int nbm = (NM + 1023) / 1024, nbu = (NU + 1023) / 1024;
  k_scan_part<<<nbm, 256, 0, stream>>>(cnt_m, off_m, bs_m, NM);
  k_scan_part<<<nbu, 256, 0, stream>>>(cnt_u, off_u, bs_u, NU);
  k_scan_top<<<1, 64, 0, stream>>>(bs_m, nbm);
  k_scan_top<<<1, 64, 0, stream>>>(bs_u, nbu);
  k_scan_add<<<(NM + 1 + 255) / 256, 256, 0, stream>>>(off_m, cur_m, bs_m, NM, E);
  k_scan_add<<<(NU + 1 + 255) / 256, 256, 0, stream>>>(off_u, cur_u, bs_u, NU, E);
  k_scatter<<<gE, 256, 0, stream>>>(esrc, edst, cur_u, cur_m, nbr_u, nbr_m, E);

  k_movie_init<<<(NM + 3) / 4, 256, 0, stream>>>(movie_x, lin_W, lin_b, movie_emb, x_movie);

  int gAgg = (NM + NU + 3) / 4;
  // layer 1 (ReLU): sources are the layer-0 features
  k_agg_dual<1><<<gAgg, 256, 0, stream>>>(user_emb, x_movie,
                                          nbr_m, off_m, W1um_l, W1um_r, b1um, m1,
                                          nbr_u, off_u, W1mu_l, W1mu_r, b1mu, u1);
  // layer 2 (no activation): sources are the layer-1 features
  k_agg_dual<0><<<gAgg, 256, 0, stream>>>(u1, m1,
                                          nbr_m, off_m, W2um_l, W2um_r, b2um, m2,
                                          nbr_u, off_u, W2mu_l, W2mu_r, b2mu, u2);

  // 16 edges per 256-thread block -> (L+15)/16 blocks
  k_dot<<<(L + 15) / 16, 256, 0, stream>>>(u2, m2, eli_u, eli_m, (float*)d_out, L);
}

// Round 4
// 1963.794 us; speedup vs baseline: 1.3192x; 1.0894x over previous
//
#include <hip/hip_runtime.h>

#define NU 100000
#define NM 50000

__device__ __forceinline__ float bcastf(float v, int lane) {
  return __int_as_float(__builtin_amdgcn_readlane(__float_as_int(v), lane));
}
__device__ __forceinline__ unsigned short f2bf(float f) {
  unsigned u = __float_as_uint(f);
  u = u + 0x7FFF + ((u >> 16) & 1);  // round-to-nearest-even
  return (unsigned short)(u >> 16);
}
__device__ __forceinline__ float bf2f(unsigned short b) {
  return __uint_as_float(((unsigned)b) << 16);
}

__global__ void k_count(const int* __restrict__ src, const int* __restrict__ dst,
                        int* cnt_u, int* cnt_m, int E) {
  int e = blockIdx.x * blockDim.x + threadIdx.x;
  if (e < E) {
    atomicAdd(&cnt_u[src[e]], 1);
    atomicAdd(&cnt_m[dst[e]], 1);
  }
}

__global__ void k_scan_part(const int* __restrict__ cnt, int* __restrict__ off,
                            int* __restrict__ bsum, int n) {
  __shared__ int wsum[4];
  int t = threadIdx.x;
  int base = blockIdx.x * 1024 + t * 4;
  int v0 = (base + 0 < n) ? cnt[base + 0] : 0;
  int v1 = (base + 1 < n) ? cnt[base + 1] : 0;
  int v2 = (base + 2 < n) ? cnt[base + 2] : 0;
  int v3 = (base + 3 < n) ? cnt[base + 3] : 0;
  int s = v0 + v1 + v2 + v3;
  int lane = t & 63;
  int inc = s;
  #pragma unroll
  for (int d = 1; d < 64; d <<= 1) {
    int x = __shfl_up(inc, d);
    if (lane >= d) inc += x;
  }
  int wid = t >> 6;
  if (lane == 63) wsum[wid] = inc;
  __syncthreads();
  int woff = 0;
  for (int i = 0; i < wid; i++) woff += wsum[i];
  int excl = woff + inc - s;
  if (base + 0 < n) off[base + 0] = excl;
  if (base + 1 < n) off[base + 1] = excl + v0;
  if (base + 2 < n) off[base + 2] = excl + v0 + v1;
  if (base + 3 < n) off[base + 3] = excl + v0 + v1 + v2;
  if (t == 255) bsum[blockIdx.x] = woff + inc;
}

__global__ void k_scan_top(int* bsum, int nb) {
  int lane = threadIdx.x;  // block of 64
  int carry = 0;
  for (int base = 0; base < nb; base += 64) {
    int i = base + lane;
    int v = (i < nb) ? bsum[i] : 0;
    int inc = v;
    #pragma unroll
    for (int d = 1; d < 64; d <<= 1) {
      int x = __shfl_up(inc, d);
      if (lane >= d) inc += x;
    }
    if (i < nb) bsum[i] = carry + inc - v;
    carry += __shfl(inc, 63);
  }
}

__global__ void k_scan_add(int* __restrict__ off, int* __restrict__ cur,
                           const int* __restrict__ bsum, int n, int total) {
  int i = blockIdx.x * blockDim.x + threadIdx.x;
  if (i < n) {
    int v = off[i] + bsum[i >> 10];
    off[i] = v;
    cur[i] = v;
  } else if (i == n) {
    off[n] = total;
  }
}

__global__ void k_scatter(const int* __restrict__ src, const int* __restrict__ dst,
                          int* cur_u, int* cur_m,
                          int* __restrict__ nbr_u, int* __restrict__ nbr_m, int E) {
  int e = blockIdx.x * blockDim.x + threadIdx.x;
  if (e < E) {
    int s = src[e], d = dst[e];
    int pu = atomicAdd(&cur_u[s], 1);
    nbr_u[pu] = d;
    int pm = atomicAdd(&cur_m[d], 1);
    nbr_m[pm] = s;
  }
}

// f32 -> bf16 table conversion, 4 elems/thread
__global__ void k_tobf4(const float4* __restrict__ in, unsigned short* __restrict__ out, int n4) {
  int i = blockIdx.x * blockDim.x + threadIdx.x;
  if (i < n4) {
    float4 v = in[i];
    ushort4 o;
    o.x = f2bf(v.x); o.y = f2bf(v.y); o.z = f2bf(v.z); o.w = f2bf(v.w);
    *(ushort4*)(out + (size_t)i * 4) = o;
  }
}

// x_movie(bf16) = movie_x @ lin_W.T + lin_b + movie_emb  (wave per movie, lane = h)
__global__ void k_movie_init(const float* __restrict__ movie_x,
                             const float* __restrict__ lin_W,
                             const float* __restrict__ lin_b,
                             const float* __restrict__ movie_emb,
                             unsigned short* __restrict__ x_movie) {
  int w = (blockIdx.x * blockDim.x + threadIdx.x) >> 6;
  int h = threadIdx.x & 63;
  if (w >= NM) return;
  float acc = lin_b[h] + movie_emb[(size_t)w * 64 + h];
  const float* mx = movie_x + (size_t)w * 20;
  const float* lw = lin_W + (size_t)h * 20;
  #pragma unroll
  for (int f = 0; f < 20; f++) acc += mx[f] * lw[f];
  x_movie[(size_t)w * 64 + h] = f2bf(acc);
}

// One wave per destination node (movie dests then user dests in one grid).
// lane = feature h. All gather tables are bf16 (128B rows) to halve the
// L2-miss-path bytes, which round-3 counters showed is the limiter
// (FETCH 525MB @ ~810GB/s per dispatch). Neighbor indices preloaded
// coalesced, broadcast via readlane -> SGPR-base gathers; 16 independent
// accumulator chains; accumulation + transform in f32.
template <int RELU, int OUT_BF>
__global__ void __launch_bounds__(256)
k_agg_dual(const unsigned short* __restrict__ xu, const unsigned short* __restrict__ xm,
           const int* __restrict__ nbrM, const int* __restrict__ offM,
           const float* __restrict__ WlM, const float* __restrict__ WrM,
           const float* __restrict__ bM, void* __restrict__ outM,
           const int* __restrict__ nbrU, const int* __restrict__ offU,
           const float* __restrict__ WlU, const float* __restrict__ WrU,
           const float* __restrict__ bU, void* __restrict__ outU) {
  int gw = (blockIdx.x * blockDim.x + threadIdx.x) >> 6;
  int h = threadIdx.x & 63;
  if (gw >= NM + NU) return;  // wave-uniform
  const unsigned short* xsrc;
  const unsigned short* xdst;
  const int* nbr;
  const int* off;
  const float* Wl;
  const float* Wr;
  const float* bias;
  void* out;
  int w;
  if (gw < NM) {
    w = gw; xsrc = xu; xdst = xm; nbr = nbrM; off = offM;
    Wl = WlM; Wr = WrM; bias = bM; out = outM;
  } else {
    w = gw - NM; xsrc = xm; xdst = xu; nbr = nbrU; off = offU;
    Wl = WlU; Wr = WrU; bias = bU; out = outU;
  }
  int s = off[w], e = off[w + 1];
  float a[16];
  #pragma unroll
  for (int i = 0; i < 16; i++) a[i] = 0.f;
  for (int base = s; base < e; base += 64) {
    int cn = e - base;
    if (cn > 64) cn = 64;
    int my = nbr[base + (h < cn ? h : 0)];  // one coalesced load per 64 nbrs
    for (int g = 0; g < cn; g += 16) {
      int lim = cn - 1;
      int j[16];
      #pragma unroll
      for (int i = 0; i < 16; i++) j[i] = __builtin_amdgcn_readlane(my, min(g + i, lim));
      float v[16];
      #pragma unroll
      for (int i = 0; i < 16; i++) v[i] = bf2f(xsrc[(size_t)j[i] * 64 + h]);
      #pragma unroll
      for (int i = 0; i < 16; i++) a[i] += (g + i < cn) ? v[i] : 0.f;
    }
  }
  #pragma unroll
  for (int d = 8; d >= 1; d >>= 1) {
    #pragma unroll
    for (int i = 0; i < 8; i++) {
      if (i < d) a[i] += a[i + d];
    }
  }
  float sum = a[0];
  float inv = 1.0f / fmaxf((float)(e - s), 1.0f);
  float mean = sum * inv;
  float dv = bf2f(xdst[(size_t)w * 64 + h]);
  // transform epilogue: weight rows in VGPRs, broadcast activations via readlane
  float wl[64], wr[64];
  const float4* wl4 = (const float4*)(Wl + (size_t)h * 64);
  const float4* wr4 = (const float4*)(Wr + (size_t)h * 64);
  #pragma unroll
  for (int i = 0; i < 16; i++) {
    float4 a4 = wl4[i];
    wl[4 * i] = a4.x; wl[4 * i + 1] = a4.y; wl[4 * i + 2] = a4.z; wl[4 * i + 3] = a4.w;
    float4 c4 = wr4[i];
    wr[4 * i] = c4.x; wr[4 * i + 1] = c4.y; wr[4 * i + 2] = c4.z; wr[4 * i + 3] = c4.w;
  }
  float acc = bias[h];
  #pragma unroll
  for (int kk = 0; kk < 64; kk++) {
    acc += bcastf(mean, kk) * wl[kk];
    acc += bcastf(dv, kk) * wr[kk];
  }
  if (RELU) acc = fmaxf(acc, 0.0f);
  if (OUT_BF)
    ((unsigned short*)out)[(size_t)w * 64 + h] = f2bf(acc);
  else
    ((float*)out)[(size_t)w * 64 + h] = acc;
}

// 16 lanes per edge: float4 row reads (256B contiguous), shfl_xor reduce,
// 4 consecutive stores per wave. 16 edges per 256-thread block.
__global__ void __launch_bounds__(256)
k_dot(const float* __restrict__ u2, const float* __restrict__ m2,
      const int* __restrict__ eu, const int* __restrict__ em,
      float* __restrict__ out, int L) {
  int wave = (blockIdx.x * blockDim.x + threadIdx.x) >> 6;
  int lane = threadIdx.x & 63;
  int sub = lane & 15;
  int l = wave * 4 + (lane >> 4);
  int lc = l < L ? l : (L - 1);
  int iu = eu[lc], im = em[lc];
  float4 x = ((const float4*)(u2 + (size_t)iu * 64))[sub];
  float4 y = ((const float4*)(m2 + (size_t)im * 64))[sub];
  float s = x.x * y.x + x.y * y.y + x.z * y.z + x.w * y.w;
  s += __shfl_xor(s, 1);
  s += __shfl_xor(s, 2);
  s += __shfl_xor(s, 4);
  s += __shfl_xor(s, 8);
  if (sub == 0 && l < L) out[l] = s;
}

extern "C" void kernel_launch(void* const* d_in, const int* in_sizes, int n_in,
                              void* d_out, int out_size, void* d_ws, size_t ws_size,
                              hipStream_t stream) {
  const float* movie_x   = (const float*)d_in[2];
  const int*   esrc      = (const int*)d_in[3];
  const int*   edst      = (const int*)d_in[4];
  const int*   eli_u     = (const int*)d_in[5];
  const int*   eli_m     = (const int*)d_in[6];
  const float* user_emb  = (const float*)d_in[7];
  const float* movie_emb = (const float*)d_in[8];
  const float* lin_W     = (const float*)d_in[9];
  const float* lin_b     = (const float*)d_in[10];
  const float* W1um_l = (const float*)d_in[11];
  const float* W1um_r = (const float*)d_in[12];
  const float* W1mu_l = (const float*)d_in[13];
  const float* W1mu_r = (const float*)d_in[14];
  const float* W2um_l = (const float*)d_in[15];
  const float* W2um_r = (const float*)d_in[16];
  const float* W2mu_l = (const float*)d_in[17];
  const float* W2mu_r = (const float*)d_in[18];
  const float* b1um = (const float*)d_in[19];
  const float* b1mu = (const float*)d_in[20];
  const float* b2um = (const float*)d_in[21];
  const float* b2mu = (const float*)d_in[22];
  const int E = in_sizes[3];
  const int L = in_sizes[5];

  char* ws = (char*)d_ws;
  size_t o = 0;
  auto alloc = [&](size_t bytes) -> void* {
    void* p = ws + o;
    o = (o + bytes + 255) & ~(size_t)255;
    return p;
  };
  unsigned short* uemb_bf   = (unsigned short*)alloc((size_t)NU * 64 * 2);
  unsigned short* xmovie_bf = (unsigned short*)alloc((size_t)NM * 64 * 2);
  unsigned short* m1_bf     = (unsigned short*)alloc((size_t)NM * 64 * 2);
  unsigned short* u1_bf     = (unsigned short*)alloc((size_t)NU * 64 * 2);
  float* m2 = (float*)alloc((size_t)NM * 64 * 4);
  float* u2 = (float*)alloc((size_t)NU * 64 * 4);
  int* cnt_m = (int*)alloc((size_t)NM * 4);
  int* cnt_u = (int*)alloc((size_t)NU * 4);
  int* off_m = (int*)alloc((size_t)(NM + 1) * 4);
  int* off_u = (int*)alloc((size_t)(NU + 1) * 4);
  int* cur_m = (int*)alloc((size_t)NM * 4);
  int* cur_u = (int*)alloc((size_t)NU * 4);
  int* bs_m  = (int*)alloc(4096);
  int* bs_u  = (int*)alloc(4096);
  int* nbr_m = (int*)alloc((size_t)E * 4);
  int* nbr_u = (int*)alloc((size_t)E * 4);

  hipMemsetAsync(cnt_m, 0, (size_t)NM * 4, stream);
  hipMemsetAsync(cnt_u, 0, (size_t)NU * 4, stream);

  int gE = (E + 255) / 256;
  k_count<<<gE, 256, 0, stream>>>(esrc, edst, cnt_u, cnt_m, E);

  int nbm = (NM + 1023) / 1024, nbu = (NU + 1023) / 1024;
  k_scan_part<<<nbm, 256, 0, stream>>>(cnt_m, off_m, bs_m, NM);
  k_scan_part<<<nbu, 256, 0, stream>>>(cnt_u, off_u, bs_u, NU);
  k_scan_top<<<1, 64, 0, stream>>>(bs_m, nbm);
  k_scan_top<<<1, 64, 0, stream>>>(bs_u, nbu);
  k_scan_add<<<(NM + 1 + 255) / 256, 256, 0, stream>>>(off_m, cur_m, bs_m, NM, E);
  k_scan_add<<<(NU + 1 + 255) / 256, 256, 0, stream>>>(off_u, cur_u, bs_u, NU, E);
  k_scatter<<<gE, 256, 0, stream>>>(esrc, edst, cur_u, cur_m, nbr_u, nbr_m, E);

  // bf16 gather tables
  int n4u = NU * 16;  // NU*64/4
  k_tobf4<<<(n4u + 255) / 256, 256, 0, stream>>>((const float4*)user_emb, uemb_bf, n4u);
  k_movie_init<<<(NM + 3) / 4, 256, 0, stream>>>(movie_x, lin_W, lin_b, movie_emb, xmovie_bf);

  int gAgg = (NM + NU + 3) / 4;
  // layer 1 (ReLU), bf16 outputs (they are layer-2 gather tables)
  k_agg_dual<1, 1><<<gAgg, 256, 0, stream>>>(uemb_bf, xmovie_bf,
                                             nbr_m, off_m, W1um_l, W1um_r, b1um, m1_bf,
                                             nbr_u, off_u, W1mu_l, W1mu_r, b1mu, u1_bf);
  // layer 2 (no activation), f32 outputs for the dot
  k_agg_dual<0, 0><<<gAgg, 256, 0, stream>>>(u1_bf, m1_bf,
                                             nbr_m, off_m, W2um_l, W2um_r, b2um, m2,
                                             nbr_u, off_u, W2mu_l, W2mu_r, b2mu, u2);

  // 16 edges per 256-thread block
  k_dot<<<(L + 15) / 16, 256, 0, stream>>>(u2, m2, eli_u, eli_m, (float*)d_out, L);
}